// Round 3
// baseline (872.014 us; speedup 1.0000x reference)
//
#include <hip/hip_runtime.h>
#include <math.h>

// Workspace layout (floats):
//  [0..24]   W  = diag(1/sqrt(s)) * V^T   (whitening matrix)
//  [25..29]  P  mask (1.0 if eigenvalue > 0 else 0.0)
//  [32..36]  cond_g accumulator (atomic)
//  [40..54]  G accumulator, upper triangle row-major (15 entries, atomic)
//  [64..68]  x  solution of G x = cond_g

#define WS_W  0
#define WS_P  25
#define WS_CG 32
#define WS_G  40
#define WS_X  64

typedef float fvec4 __attribute__((ext_vector_type(4)));

// ---------------------------------------------------------------------------
// Kernel 1: 5x5 symmetric eigendecomposition (cyclic Jacobi, double precision),
// build W, P; zero the accumulators (ws is poisoned 0xAA before every launch).
// ---------------------------------------------------------------------------
__global__ void kwng_prep(const float* __restrict__ K, float* __restrict__ ws) {
    if (blockIdx.x != 0 || threadIdx.x != 0) return;
    double a[5][5], V[5][5];
    for (int i = 0; i < 5; i++)
        for (int j = 0; j < 5; j++) {
            a[i][j] = (double)K[i * 5 + j];
            V[i][j] = (i == j) ? 1.0 : 0.0;
        }
    for (int sweep = 0; sweep < 30; sweep++) {
        double off = 0.0;
        for (int p = 0; p < 5; p++)
            for (int q = p + 1; q < 5; q++) off += a[p][q] * a[p][q];
        if (off < 1e-26) break;
        for (int p = 0; p < 5; p++) {
            for (int q = p + 1; q < 5; q++) {
                double apq = a[p][q];
                if (fabs(apq) < 1e-300) continue;
                double tau = (a[q][q] - a[p][p]) / (2.0 * apq);
                double t = ((tau >= 0.0) ? 1.0 : -1.0) /
                           (fabs(tau) + sqrt(1.0 + tau * tau));
                double c = 1.0 / sqrt(1.0 + t * t);
                double s = t * c;
                for (int k = 0; k < 5; k++) {
                    double akp = a[k][p], akq = a[k][q];
                    a[k][p] = c * akp - s * akq;
                    a[k][q] = s * akp + c * akq;
                }
                for (int k = 0; k < 5; k++) {
                    double apk = a[p][k], aqk = a[q][k];
                    a[p][k] = c * apk - s * aqk;
                    a[q][k] = s * apk + c * aqk;
                }
                for (int k = 0; k < 5; k++) {
                    double vkp = V[k][p], vkq = V[k][q];
                    V[k][p] = c * vkp - s * vkq;
                    V[k][q] = s * vkp + c * vkq;
                }
            }
        }
    }
    for (int i = 0; i < 5; i++) {
        double si = a[i][i];
        int keep = (si > 0.0);
        double inv = keep ? 1.0 / sqrt(si) : 0.0;
        ws[WS_P + i] = keep ? 1.0f : 0.0f;
        for (int j = 0; j < 5; j++)
            ws[WS_W + i * 5 + j] = (float)(inv * V[j][i]);
    }
    for (int i = 0; i < 5; i++)  ws[WS_CG + i] = 0.0f;
    for (int i = 0; i < 15; i++) ws[WS_G + i] = 0.0f;
}

// ---------------------------------------------------------------------------
// Per-column helpers
// ---------------------------------------------------------------------------
__device__ __forceinline__ void col_accum(const float W[25],
                                          float c0, float c1, float c2,
                                          float c3, float c4, float gc,
                                          float cg[5], float Gu[15]) {
    float tt[5];
#pragma unroll
    for (int i = 0; i < 5; i++)
        tt[i] = W[i * 5 + 0] * c0 + W[i * 5 + 1] * c1 + W[i * 5 + 2] * c2 +
                W[i * 5 + 3] * c3 + W[i * 5 + 4] * c4;
    float ss = tt[0] * tt[0] + tt[1] * tt[1] + tt[2] * tt[2] +
               tt[3] * tt[3] + tt[4] * tt[4];
    float dv = 1.0f / (sqrtf(ss) + 1e-8f);
    float dg = dv * gc;
#pragma unroll
    for (int i = 0; i < 5; i++) cg[i] += tt[i] * dg;
    int idx = 0;
#pragma unroll
    for (int i = 0; i < 5; i++) {
        float tdi = tt[i] * dv;
#pragma unroll
        for (int l = i; l < 5; l++) Gu[idx++] += tdi * tt[l];
    }
}

__device__ __forceinline__ void col_accum4(const float W[25],
                                           float4 t0, float4 t1, float4 t2,
                                           float4 t3, float4 t4, float4 gv,
                                           float cg[5], float Gu[15]) {
    col_accum(W, t0.x, t1.x, t2.x, t3.x, t4.x, gv.x, cg, Gu);
    col_accum(W, t0.y, t1.y, t2.y, t3.y, t4.y, gv.y, cg, Gu);
    col_accum(W, t0.z, t1.z, t2.z, t3.z, t4.z, gv.z, cg, Gu);
    col_accum(W, t0.w, t1.w, t2.w, t3.w, t4.w, gv.w, cg, Gu);
}

__device__ __forceinline__ float col_out(const float W[25], const float x[5],
                                         float c0, float c1, float c2,
                                         float c3, float c4, float gc) {
    float tt[5];
#pragma unroll
    for (int i = 0; i < 5; i++)
        tt[i] = W[i * 5 + 0] * c0 + W[i * 5 + 1] * c1 + W[i * 5 + 2] * c2 +
                W[i * 5 + 3] * c3 + W[i * 5 + 4] * c4;
    float ss = tt[0] * tt[0] + tt[1] * tt[1] + tt[2] * tt[2] +
               tt[3] * tt[3] + tt[4] * tt[4];
    float dv = 1.0f / (sqrtf(ss) + 1e-8f);
    float xc = tt[0] * x[0] + tt[1] * x[1] + tt[2] * x[2] +
               tt[3] * x[3] + tt[4] * x[4];
    // BETA = -1: (g - BETA*c)/EPS = (g + c) * 1e5
    return dv * (gc + xc) * (1.0f / 1e-5f);
}

__device__ __forceinline__ fvec4 col_out4(const float W[25], const float x[5],
                                          float4 t0, float4 t1, float4 t2,
                                          float4 t3, float4 t4, float4 gv) {
    fvec4 o;
    o.x = col_out(W, x, t0.x, t1.x, t2.x, t3.x, t4.x, gv.x);
    o.y = col_out(W, x, t0.y, t1.y, t2.y, t3.y, t4.y, gv.y);
    o.z = col_out(W, x, t0.z, t1.z, t2.z, t3.z, t4.z, gv.z);
    o.w = col_out(W, x, t0.w, t1.w, t2.w, t3.w, t4.w, gv.w);
    return o;
}

// ---------------------------------------------------------------------------
// Kernel 2: streaming reduction.
// Contiguous block-owned tiles (chunks 4 KB apart, 16 KB contiguous per row
// per tile — no more 8-MiB congruent jumps). All 24 float4 loads of a tile
// are issued back-to-back and pinned by sched_barrier(0) so the compiler
// cannot split the batch; __launch_bounds__(256,3) gives the VGPR headroom
// (~170) to hold the whole 96-VGPR payload. In-flight target: 12 waves/CU
// x 24 KB >> 22 KB/CU Little's-law requirement for 6.3 TB/s.
// ---------------------------------------------------------------------------
__launch_bounds__(256, 3)
__global__ void kwng_pass1(const float* __restrict__ T, const float* __restrict__ g,
                           float* __restrict__ ws, int D) {
    float W[25];
#pragma unroll
    for (int i = 0; i < 25; i++) W[i] = ws[WS_W + i];

    float cg[5] = {0, 0, 0, 0, 0};
    float Gu[15];
#pragma unroll
    for (int i = 0; i < 15; i++) Gu[i] = 0.0f;

    const int NV = D >> 2;  // float4 columns
    const float4* T0 = (const float4*)T;
    const float4* T1 = (const float4*)(T + (size_t)D);
    const float4* T2 = (const float4*)(T + 2 * (size_t)D);
    const float4* T3 = (const float4*)(T + 3 * (size_t)D);
    const float4* T4 = (const float4*)(T + 4 * (size_t)D);
    const float4* G4 = (const float4*)g;

    // Block-owned contiguous segment.
    const int seg = NV / (int)gridDim.x;          // 2048 for NV=4M, grid=2048
    const int seg0 = (int)blockIdx.x * seg;
    const int tile = 4 * (int)blockDim.x;         // 1024 float4 per tile

    for (int t = 0; t < seg; t += tile) {
        int base = seg0 + t + (int)threadIdx.x;
        int va = base, vb = base + 256, vc = base + 512, vd = base + 768;
        if (vd < NV && (t + tile) <= seg) {
            float4 a0 = T0[va], b0 = T0[vb], c0 = T0[vc], d0 = T0[vd];
            float4 a1 = T1[va], b1 = T1[vb], c1 = T1[vc], d1 = T1[vd];
            float4 a2 = T2[va], b2 = T2[vb], c2 = T2[vc], d2 = T2[vd];
            float4 a3 = T3[va], b3 = T3[vb], c3 = T3[vc], d3 = T3[vd];
            float4 a4 = T4[va], b4 = T4[vb], c4 = T4[vc], d4 = T4[vd];
            float4 ag = G4[va], bg = G4[vb], cq = G4[vc], dg = G4[vd];
            __builtin_amdgcn_sched_barrier(0);   // pin: all 24 loads precede uses
            col_accum4(W, a0, a1, a2, a3, a4, ag, cg, Gu);
            col_accum4(W, b0, b1, b2, b3, b4, bg, cg, Gu);
            col_accum4(W, c0, c1, c2, c3, c4, cq, cg, Gu);
            col_accum4(W, d0, d1, d2, d3, d4, dg, cg, Gu);
        } else {
            // Guarded tail (not taken for D = 16,777,216; kept for safety).
#pragma unroll
            for (int k = 0; k < 4; k++) {
                int v = base + k * 256;
                if (v < seg0 + seg && v < NV) {
                    float4 t0 = T0[v], t1 = T1[v], t2 = T2[v], t3 = T3[v],
                           t4 = T4[v];
                    float4 gv = G4[v];
                    col_accum4(W, t0, t1, t2, t3, t4, gv, cg, Gu);
                }
            }
        }
    }

    // Block reduction: wave shuffle (64-wide) then LDS across 4 waves.
    __shared__ float red[4][20];
    float vals[20];
#pragma unroll
    for (int i = 0; i < 20; i++) {
        float val = (i < 5) ? cg[i] : Gu[i - 5];
#pragma unroll
        for (int off = 32; off > 0; off >>= 1) val += __shfl_down(val, off);
        vals[i] = val;
    }
    int lane = threadIdx.x & 63;
    int wid = threadIdx.x >> 6;
    if (lane == 0) {
#pragma unroll
        for (int i = 0; i < 20; i++) red[wid][i] = vals[i];
    }
    __syncthreads();
    if (threadIdx.x == 0) {
#pragma unroll
        for (int i = 0; i < 20; i++) {
            float s = red[0][i] + red[1][i] + red[2][i] + red[3][i];
            atomicAdd(&ws[(i < 5) ? (WS_CG + i) : (WS_G + i - 5)], s);
        }
    }
}

// ---------------------------------------------------------------------------
// Kernel 3: form G (+eps*P on diagonal), Gauss-Jordan solve in double.
// ---------------------------------------------------------------------------
__global__ void kwng_solve(float* __restrict__ ws) {
    if (blockIdx.x != 0 || threadIdx.x != 0) return;
    double A[5][6];
    int idx = 0;
    for (int i = 0; i < 5; i++)
        for (int l = i; l < 5; l++) {
            double v = (double)ws[WS_G + idx++];
            A[i][l] = v;
            A[l][i] = v;
        }
    for (int i = 0; i < 5; i++)
        A[i][i] += 1e-5 * (double)ws[WS_P + i];
    for (int i = 0; i < 5; i++) A[i][5] = (double)ws[WS_CG + i];

    for (int k = 0; k < 5; k++) {
        int piv = k;
        for (int r = k + 1; r < 5; r++)
            if (fabs(A[r][k]) > fabs(A[piv][k])) piv = r;
        if (piv != k)
            for (int j = 0; j < 6; j++) {
                double tmp = A[k][j]; A[k][j] = A[piv][j]; A[piv][j] = tmp;
            }
        double d = A[k][k];
        double dinv = (d != 0.0) ? 1.0 / d : 0.0;
        for (int j = k; j < 6; j++) A[k][j] *= dinv;
        for (int r = 0; r < 5; r++) {
            if (r == k) continue;
            double f = A[r][k];
            for (int j = k; j < 6; j++) A[r][j] -= f * A[k][j];
        }
    }
    for (int i = 0; i < 5; i++) ws[WS_X + i] = (float)A[i][5];
}

// ---------------------------------------------------------------------------
// Kernel 4: streaming output, same forced-batch treatment as pass1:
// __launch_bounds__(256,3) for VGPR headroom + sched_barrier(0) pinning all
// 24 loads before first use. Block order REVERSED so the first addresses
// read are the last ones pass1 touched (Infinity-Cache reuse). Nontemporal
// stores keep the write stream from evicting L3-resident T/g.
// ---------------------------------------------------------------------------
__launch_bounds__(256, 3)
__global__ void kwng_pass2(const float* __restrict__ T, const float* __restrict__ g,
                           const float* __restrict__ ws, float* __restrict__ out,
                           int D) {
    float W[25], x[5];
#pragma unroll
    for (int i = 0; i < 25; i++) W[i] = ws[WS_W + i];
#pragma unroll
    for (int i = 0; i < 5; i++) x[i] = ws[WS_X + i];

    const int NV = D >> 2;
    int bid = (int)gridDim.x - 1 - (int)blockIdx.x;  // reversed for L3 locality
    int base = bid * (int)(blockDim.x * 4) + (int)threadIdx.x;

    const float4* T0 = (const float4*)T;
    const float4* T1 = (const float4*)(T + (size_t)D);
    const float4* T2 = (const float4*)(T + 2 * (size_t)D);
    const float4* T3 = (const float4*)(T + 3 * (size_t)D);
    const float4* T4 = (const float4*)(T + 4 * (size_t)D);
    const float4* G4 = (const float4*)g;
    fvec4* O4 = (fvec4*)out;

    int va = base, vb = base + 256, vc = base + 512, vd = base + 768;
    if (vd < NV) {
        // Fast path: all 24 loads issued before first use, pinned.
        float4 a0 = T0[va], b0 = T0[vb], c0 = T0[vc], d0 = T0[vd];
        float4 a1 = T1[va], b1 = T1[vb], c1 = T1[vc], d1 = T1[vd];
        float4 a2 = T2[va], b2 = T2[vb], c2 = T2[vc], d2 = T2[vd];
        float4 a3 = T3[va], b3 = T3[vb], c3 = T3[vc], d3 = T3[vd];
        float4 a4 = T4[va], b4 = T4[vb], c4 = T4[vc], d4 = T4[vd];
        float4 ag = G4[va], bg = G4[vb], cq = G4[vc], dg = G4[vd];
        __builtin_amdgcn_sched_barrier(0);
        __builtin_nontemporal_store(col_out4(W, x, a0, a1, a2, a3, a4, ag), O4 + va);
        __builtin_nontemporal_store(col_out4(W, x, b0, b1, b2, b3, b4, bg), O4 + vb);
        __builtin_nontemporal_store(col_out4(W, x, c0, c1, c2, c3, c4, cq), O4 + vc);
        __builtin_nontemporal_store(col_out4(W, x, d0, d1, d2, d3, d4, dg), O4 + vd);
    } else {
        // Guarded tail (not taken for D = 16,777,216; kept for safety).
#pragma unroll
        for (int k = 0; k < 4; k++) {
            int v = base + k * 256;
            if (v < NV) {
                float4 t0 = T0[v], t1 = T1[v], t2 = T2[v], t3 = T3[v], t4 = T4[v];
                float4 gv = G4[v];
                __builtin_nontemporal_store(col_out4(W, x, t0, t1, t2, t3, t4, gv),
                                            O4 + v);
            }
        }
    }
}

// ---------------------------------------------------------------------------
extern "C" void kernel_launch(void* const* d_in, const int* in_sizes, int n_in,
                              void* d_out, int out_size, void* d_ws, size_t ws_size,
                              hipStream_t stream) {
    const float* K = (const float*)d_in[0];
    const float* T = (const float*)d_in[1];
    const float* g = (const float*)d_in[2];
    float* out = (float*)d_out;
    float* ws = (float*)d_ws;
    const int D = in_sizes[2];  // 16,777,216
    const int NV = D >> 2;

    kwng_prep<<<1, 1, 0, stream>>>(K, ws);

    // Pass 1: 2048 blocks, each owns a contiguous 2048-float4 segment
    // (2 tiles of 1024).
    kwng_pass1<<<2048, 256, 0, stream>>>(T, g, ws, D);

    kwng_solve<<<1, 1, 0, stream>>>(ws);

    // Pass 2: 4 float4 columns per thread, reversed block order.
    int blocks2 = (NV + 1023) / 1024;  // 4096
    kwng_pass2<<<blocks2, 256, 0, stream>>>(T, g, ws, out, D);
}

// Round 4
// 852.259 us; speedup vs baseline: 1.0232x; 1.0232x over previous
//
#include <hip/hip_runtime.h>
#include <math.h>

// Workspace layout (floats):
//  [0..24]   W  = diag(1/sqrt(s)) * V^T   (whitening matrix)
//  [25..29]  P  mask (1.0 if eigenvalue > 0 else 0.0)
//  [32..36]  cond_g accumulator (atomic)
//  [40..54]  G accumulator, upper triangle row-major (15 entries, atomic)
//  [64..68]  x  solution of G x = cond_g

#define WS_W  0
#define WS_P  25
#define WS_CG 32
#define WS_G  40
#define WS_X  64

typedef float fvec4 __attribute__((ext_vector_type(4)));

// Tile geometry: 512 float4 columns per tile, 6 streams (T0..T4, g).
// LDS = 6 rows x 8192 B = 49152 B  ->  3 blocks/CU.
#define TILE_F4   512
#define ROW_BYTES 8192

// global -> LDS direct copy, 16 B per lane; LDS dest is wave-uniform base,
// HW writes lane l at dst + l*16 (guide §5; m97). Decouples MLP from VGPRs.
__device__ __forceinline__ void gload_lds16(const float* gsrc, void* ldsdst) {
    __builtin_amdgcn_global_load_lds(
        (const __attribute__((address_space(1))) unsigned int*)gsrc,
        (__attribute__((address_space(3))) unsigned int*)ldsdst,
        16, 0, 0);
}

// ---------------------------------------------------------------------------
// Kernel 1: 5x5 symmetric eigendecomposition (cyclic Jacobi, double precision),
// build W, P; zero the accumulators (ws is poisoned 0xAA before every launch).
// ---------------------------------------------------------------------------
__global__ void kwng_prep(const float* __restrict__ K, float* __restrict__ ws) {
    if (blockIdx.x != 0 || threadIdx.x != 0) return;
    double a[5][5], V[5][5];
    for (int i = 0; i < 5; i++)
        for (int j = 0; j < 5; j++) {
            a[i][j] = (double)K[i * 5 + j];
            V[i][j] = (i == j) ? 1.0 : 0.0;
        }
    for (int sweep = 0; sweep < 30; sweep++) {
        double off = 0.0;
        for (int p = 0; p < 5; p++)
            for (int q = p + 1; q < 5; q++) off += a[p][q] * a[p][q];
        if (off < 1e-26) break;
        for (int p = 0; p < 5; p++) {
            for (int q = p + 1; q < 5; q++) {
                double apq = a[p][q];
                if (fabs(apq) < 1e-300) continue;
                double tau = (a[q][q] - a[p][p]) / (2.0 * apq);
                double t = ((tau >= 0.0) ? 1.0 : -1.0) /
                           (fabs(tau) + sqrt(1.0 + tau * tau));
                double c = 1.0 / sqrt(1.0 + t * t);
                double s = t * c;
                for (int k = 0; k < 5; k++) {
                    double akp = a[k][p], akq = a[k][q];
                    a[k][p] = c * akp - s * akq;
                    a[k][q] = s * akp + c * akq;
                }
                for (int k = 0; k < 5; k++) {
                    double apk = a[p][k], aqk = a[q][k];
                    a[p][k] = c * apk - s * aqk;
                    a[q][k] = s * apk + c * aqk;
                }
                for (int k = 0; k < 5; k++) {
                    double vkp = V[k][p], vkq = V[k][q];
                    V[k][p] = c * vkp - s * vkq;
                    V[k][q] = s * vkp + c * vkq;
                }
            }
        }
    }
    for (int i = 0; i < 5; i++) {
        double si = a[i][i];
        int keep = (si > 0.0);
        double inv = keep ? 1.0 / sqrt(si) : 0.0;
        ws[WS_P + i] = keep ? 1.0f : 0.0f;
        for (int j = 0; j < 5; j++)
            ws[WS_W + i * 5 + j] = (float)(inv * V[j][i]);
    }
    for (int i = 0; i < 5; i++)  ws[WS_CG + i] = 0.0f;
    for (int i = 0; i < 15; i++) ws[WS_G + i] = 0.0f;
}

// ---------------------------------------------------------------------------
// Per-column helpers
// ---------------------------------------------------------------------------
__device__ __forceinline__ void col_accum(const float W[25],
                                          float c0, float c1, float c2,
                                          float c3, float c4, float gc,
                                          float cg[5], float Gu[15]) {
    float tt[5];
#pragma unroll
    for (int i = 0; i < 5; i++)
        tt[i] = W[i * 5 + 0] * c0 + W[i * 5 + 1] * c1 + W[i * 5 + 2] * c2 +
                W[i * 5 + 3] * c3 + W[i * 5 + 4] * c4;
    float ss = tt[0] * tt[0] + tt[1] * tt[1] + tt[2] * tt[2] +
               tt[3] * tt[3] + tt[4] * tt[4];
    float dv = 1.0f / (sqrtf(ss) + 1e-8f);
    float dg = dv * gc;
#pragma unroll
    for (int i = 0; i < 5; i++) cg[i] += tt[i] * dg;
    int idx = 0;
#pragma unroll
    for (int i = 0; i < 5; i++) {
        float tdi = tt[i] * dv;
#pragma unroll
        for (int l = i; l < 5; l++) Gu[idx++] += tdi * tt[l];
    }
}

__device__ __forceinline__ void col_accum4(const float W[25],
                                           float4 t0, float4 t1, float4 t2,
                                           float4 t3, float4 t4, float4 gv,
                                           float cg[5], float Gu[15]) {
    col_accum(W, t0.x, t1.x, t2.x, t3.x, t4.x, gv.x, cg, Gu);
    col_accum(W, t0.y, t1.y, t2.y, t3.y, t4.y, gv.y, cg, Gu);
    col_accum(W, t0.z, t1.z, t2.z, t3.z, t4.z, gv.z, cg, Gu);
    col_accum(W, t0.w, t1.w, t2.w, t3.w, t4.w, gv.w, cg, Gu);
}

__device__ __forceinline__ float col_out(const float W[25], const float x[5],
                                         float c0, float c1, float c2,
                                         float c3, float c4, float gc) {
    float tt[5];
#pragma unroll
    for (int i = 0; i < 5; i++)
        tt[i] = W[i * 5 + 0] * c0 + W[i * 5 + 1] * c1 + W[i * 5 + 2] * c2 +
                W[i * 5 + 3] * c3 + W[i * 5 + 4] * c4;
    float ss = tt[0] * tt[0] + tt[1] * tt[1] + tt[2] * tt[2] +
               tt[3] * tt[3] + tt[4] * tt[4];
    float dv = 1.0f / (sqrtf(ss) + 1e-8f);
    float xc = tt[0] * x[0] + tt[1] * x[1] + tt[2] * x[2] +
               tt[3] * x[3] + tt[4] * x[4];
    // BETA = -1: (g - BETA*c)/EPS = (g + c) * 1e5
    return dv * (gc + xc) * (1.0f / 1e-5f);
}

__device__ __forceinline__ fvec4 col_out4(const float W[25], const float x[5],
                                          float4 t0, float4 t1, float4 t2,
                                          float4 t3, float4 t4, float4 gv) {
    fvec4 o;
    o.x = col_out(W, x, t0.x, t1.x, t2.x, t3.x, t4.x, gv.x);
    o.y = col_out(W, x, t0.y, t1.y, t2.y, t3.y, t4.y, gv.y);
    o.z = col_out(W, x, t0.z, t1.z, t2.z, t3.z, t4.z, gv.z);
    o.w = col_out(W, x, t0.w, t1.w, t2.w, t3.w, t4.w, gv.w);
    return o;
}

// Stage one tile (6 streams x 8 KB) into LDS. Wave w issues 12 consecutive
// 1-KB global_load_lds units u = w*12 .. w*12+11; unit u covers row u/8,
// KB u%8 — so each wave streams LONG same-row runs (8-KB bursts), and the
// deep VGPR-free queue lets the DRAM scheduler chain row hits.
__device__ __forceinline__ void stage_tile(const float* __restrict__ T,
                                           const float* __restrict__ g,
                                           int D, size_t col0f, void* smem) {
    int wid = (int)threadIdx.x >> 6;
    int lane = (int)threadIdx.x & 63;
#pragma unroll
    for (int j = 0; j < 12; ++j) {
        int u = wid * 12 + j;
        int row = u >> 3;
        int ko = u & 7;
        const float* src = (row < 5) ? (T + (size_t)row * (size_t)D) : g;
        src += col0f + (size_t)ko * 256 + (size_t)lane * 4;
        gload_lds16(src, (char*)smem + row * ROW_BYTES + ko * 1024);
    }
}

// ---------------------------------------------------------------------------
// Kernel 2: streaming reduction via LDS-staged tiles.
// ---------------------------------------------------------------------------
__launch_bounds__(256)
__global__ void kwng_pass1(const float* __restrict__ T, const float* __restrict__ g,
                           float* __restrict__ ws, int D) {
    __shared__ float4 smem4[6 * TILE_F4];   // 49152 B -> 3 blocks/CU

    float W[25];
#pragma unroll
    for (int i = 0; i < 25; i++) W[i] = ws[WS_W + i];

    float cg[5] = {0, 0, 0, 0, 0};
    float Gu[15];
#pragma unroll
    for (int i = 0; i < 15; i++) Gu[i] = 0.0f;

    const int NV = D >> 2;              // float4 columns
    const int ntiles = NV >> 9;         // full 512-f4 tiles

    for (int tl = (int)blockIdx.x; tl < ntiles; tl += (int)gridDim.x) {
        stage_tile(T, g, D, (size_t)tl * (TILE_F4 * 4), smem4);
        __syncthreads();                // drains vmcnt: tile resident

        int t0 = (int)threadIdx.x;      // columns t0 and t0+256
        {
            float4 r0 = smem4[0 * TILE_F4 + t0], r1 = smem4[1 * TILE_F4 + t0],
                   r2 = smem4[2 * TILE_F4 + t0], r3 = smem4[3 * TILE_F4 + t0],
                   r4 = smem4[4 * TILE_F4 + t0], rg = smem4[5 * TILE_F4 + t0];
            col_accum4(W, r0, r1, r2, r3, r4, rg, cg, Gu);
        }
        {
            int t1 = t0 + 256;
            float4 r0 = smem4[0 * TILE_F4 + t1], r1 = smem4[1 * TILE_F4 + t1],
                   r2 = smem4[2 * TILE_F4 + t1], r3 = smem4[3 * TILE_F4 + t1],
                   r4 = smem4[4 * TILE_F4 + t1], rg = smem4[5 * TILE_F4 + t1];
            col_accum4(W, r0, r1, r2, r3, r4, rg, cg, Gu);
        }
        __syncthreads();                // protect LDS before next stage
    }

    // Remainder columns (none for D = 16,777,216): direct path, block 0.
    int rem0 = ntiles << 9;
    if ((int)blockIdx.x == 0) {
        const float4* T0 = (const float4*)T;
        const float4* T1 = (const float4*)(T + (size_t)D);
        const float4* T2 = (const float4*)(T + 2 * (size_t)D);
        const float4* T3 = (const float4*)(T + 3 * (size_t)D);
        const float4* T4 = (const float4*)(T + 4 * (size_t)D);
        const float4* G4 = (const float4*)g;
        for (int v = rem0 + (int)threadIdx.x; v < NV; v += 256) {
            float4 t0 = T0[v], t1 = T1[v], t2 = T2[v], t3 = T3[v], t4 = T4[v];
            float4 gv = G4[v];
            col_accum4(W, t0, t1, t2, t3, t4, gv, cg, Gu);
        }
    }

    // Block reduction: wave shuffle (64-wide) then LDS across 4 waves.
    __shared__ float red[4][20];
    float vals[20];
#pragma unroll
    for (int i = 0; i < 20; i++) {
        float val = (i < 5) ? cg[i] : Gu[i - 5];
#pragma unroll
        for (int off = 32; off > 0; off >>= 1) val += __shfl_down(val, off);
        vals[i] = val;
    }
    int lane = (int)threadIdx.x & 63;
    int wid = (int)threadIdx.x >> 6;
    if (lane == 0) {
#pragma unroll
        for (int i = 0; i < 20; i++) red[wid][i] = vals[i];
    }
    __syncthreads();
    if (threadIdx.x == 0) {
#pragma unroll
        for (int i = 0; i < 20; i++) {
            float s = red[0][i] + red[1][i] + red[2][i] + red[3][i];
            atomicAdd(&ws[(i < 5) ? (WS_CG + i) : (WS_G + i - 5)], s);
        }
    }
}

// ---------------------------------------------------------------------------
// Kernel 3: form G (+eps*P on diagonal), Gauss-Jordan solve in double.
// ---------------------------------------------------------------------------
__global__ void kwng_solve(float* __restrict__ ws) {
    if (blockIdx.x != 0 || threadIdx.x != 0) return;
    double A[5][6];
    int idx = 0;
    for (int i = 0; i < 5; i++)
        for (int l = i; l < 5; l++) {
            double v = (double)ws[WS_G + idx++];
            A[i][l] = v;
            A[l][i] = v;
        }
    for (int i = 0; i < 5; i++)
        A[i][i] += 1e-5 * (double)ws[WS_P + i];
    for (int i = 0; i < 5; i++) A[i][5] = (double)ws[WS_CG + i];

    for (int k = 0; k < 5; k++) {
        int piv = k;
        for (int r = k + 1; r < 5; r++)
            if (fabs(A[r][k]) > fabs(A[piv][k])) piv = r;
        if (piv != k)
            for (int j = 0; j < 6; j++) {
                double tmp = A[k][j]; A[k][j] = A[piv][j]; A[piv][j] = tmp;
            }
        double d = A[k][k];
        double dinv = (d != 0.0) ? 1.0 / d : 0.0;
        for (int j = k; j < 6; j++) A[k][j] *= dinv;
        for (int r = 0; r < 5; r++) {
            if (r == k) continue;
            double f = A[r][k];
            for (int j = k; j < 6; j++) A[r][j] -= f * A[k][j];
        }
    }
    for (int i = 0; i < 5; i++) ws[WS_X + i] = (float)A[i][5];
}

// ---------------------------------------------------------------------------
// Kernel 4: streaming output via the same LDS-staged tiles, reversed tile
// order (pass1's last-touched tiles are read first -> Infinity-Cache reuse).
// Nontemporal stores keep the write stream from evicting L3-resident T/g.
// ---------------------------------------------------------------------------
__launch_bounds__(256)
__global__ void kwng_pass2(const float* __restrict__ T, const float* __restrict__ g,
                           const float* __restrict__ ws, float* __restrict__ out,
                           int D) {
    __shared__ float4 smem4[6 * TILE_F4];   // 49152 B -> 3 blocks/CU

    float W[25], x[5];
#pragma unroll
    for (int i = 0; i < 25; i++) W[i] = ws[WS_W + i];
#pragma unroll
    for (int i = 0; i < 5; i++) x[i] = ws[WS_X + i];

    const int NV = D >> 2;
    const int ntiles = NV >> 9;
    fvec4* O4 = (fvec4*)out;

    for (int tl0 = (int)blockIdx.x; tl0 < ntiles; tl0 += (int)gridDim.x) {
        int tl = ntiles - 1 - tl0;          // reversed for L3 locality
        stage_tile(T, g, D, (size_t)tl * (TILE_F4 * 4), smem4);
        __syncthreads();

        int base = tl << 9;                  // first float4 column of tile
        int t0 = (int)threadIdx.x;
        {
            float4 r0 = smem4[0 * TILE_F4 + t0], r1 = smem4[1 * TILE_F4 + t0],
                   r2 = smem4[2 * TILE_F4 + t0], r3 = smem4[3 * TILE_F4 + t0],
                   r4 = smem4[4 * TILE_F4 + t0], rg = smem4[5 * TILE_F4 + t0];
            __builtin_nontemporal_store(col_out4(W, x, r0, r1, r2, r3, r4, rg),
                                        O4 + base + t0);
        }
        {
            int t1 = t0 + 256;
            float4 r0 = smem4[0 * TILE_F4 + t1], r1 = smem4[1 * TILE_F4 + t1],
                   r2 = smem4[2 * TILE_F4 + t1], r3 = smem4[3 * TILE_F4 + t1],
                   r4 = smem4[4 * TILE_F4 + t1], rg = smem4[5 * TILE_F4 + t1];
            __builtin_nontemporal_store(col_out4(W, x, r0, r1, r2, r3, r4, rg),
                                        O4 + base + t1);
        }
        __syncthreads();
    }

    // Remainder columns (none for D = 16,777,216): direct path, block 0.
    int rem0 = ntiles << 9;
    if ((int)blockIdx.x == 0) {
        const float4* T0 = (const float4*)T;
        const float4* T1 = (const float4*)(T + (size_t)D);
        const float4* T2 = (const float4*)(T + 2 * (size_t)D);
        const float4* T3 = (const float4*)(T + 3 * (size_t)D);
        const float4* T4 = (const float4*)(T + 4 * (size_t)D);
        const float4* G4 = (const float4*)g;
        for (int v = rem0 + (int)threadIdx.x; v < NV; v += 256) {
            float4 t0 = T0[v], t1 = T1[v], t2 = T2[v], t3 = T3[v], t4 = T4[v];
            float4 gv = G4[v];
            __builtin_nontemporal_store(col_out4(W, x, t0, t1, t2, t3, t4, gv),
                                        O4 + v);
        }
    }
}

// ---------------------------------------------------------------------------
extern "C" void kernel_launch(void* const* d_in, const int* in_sizes, int n_in,
                              void* d_out, int out_size, void* d_ws, size_t ws_size,
                              hipStream_t stream) {
    const float* K = (const float*)d_in[0];
    const float* T = (const float*)d_in[1];
    const float* g = (const float*)d_in[2];
    float* out = (float*)d_out;
    float* ws = (float*)d_ws;
    const int D = in_sizes[2];  // 16,777,216

    kwng_prep<<<1, 1, 0, stream>>>(K, ws);

    // Pass 1: 2048 blocks, LDS-staged tiles (8192 tiles -> 4 per block).
    kwng_pass1<<<2048, 256, 0, stream>>>(T, g, ws, D);

    kwng_solve<<<1, 1, 0, stream>>>(ws);

    // Pass 2: same staging, reversed tile order.
    kwng_pass2<<<2048, 256, 0, stream>>>(T, g, ws, out, D);
}